// Round 14
// baseline (1236.850 us; speedup 1.0000x reference)
//
#include <hip/hip_runtime.h>
#include <hip/hip_fp16.h>

// RNN_16492674416646: h_t = tanh(x_t W_ih^T + b_ih + b_hh + h_{t-1} W_hh^T),
// out_t = h_t W_out^T + b_out. T=2048, B=128, IN=2, H=200, OUT=1, fp32.
//
// R14 = R13 (16 waves, 1 n-tile/wave, fp16-W MFMA, split-fp16 h,
// bank-disjoint 9-slot ring) minus per-step VALU fat. R13 was issue-bound:
// VALU 560 cyc/SIMD/step of 1306 total (~70 instr/wave/step).
// 1) x-proj + bias folded into the MFMA's dead k-space (k=200..223 was
//    zero pad): B[200/201]=W_ih hi, B[204/205]=W_ih lo, B[202/203]=
//    bias hi/lo; ring cols 200/201/204/205 carry x_t hi/lo (written by
//    idle wave 13 one step ahead), cols 202/203 hold constant 1.0.
//    Epilogue loses the x reads + 2 fma + bias add; 0 extra MFMAs.
// 2) Drain moved to idle waves 13..15 (3 slots each, every 9 steps):
//    tile waves 0..12 run a uniform branch-free stream.
// 3) Epilogue: pre = u0+u1+v0+v1 -> tanh -> 2 ds_write_b16.
// MFMA reads A/B from AGPRs natively (ISA 10) -> parked B-frags are free;
// VGPR_Count ~52 at R13 was benign.

typedef short s8v __attribute__((ext_vector_type(8)));   // 8 x fp16 bits
typedef float f4v __attribute__((ext_vector_type(4)));

static constexpr int T = 2048;
static constexpr int B = 128;
static constexpr int H = 200;
static constexpr int NTHR = 1024;  // 16 waves
static constexpr int NT  = 13;     // n-tiles of 16 (208 >= 200)
static constexpr int KT  = 7;      // k-tiles of 32 (224)
static constexpr int HP  = 224;    // padded H (k-space)
static constexpr int RS  = 9;      // ring slots

__device__ __forceinline__ unsigned short f2h(float f) {
    const __half h = __float2half_rn(f);
    return *(const unsigned short*)&h;
}
__device__ __forceinline__ float h2f(unsigned short u) {
    const __half h = *(const __half*)&u;
    return __half2float(h);
}

__global__ __attribute__((amdgpu_flat_work_group_size(NTHR, NTHR),
                          amdgpu_waves_per_eu(4, 4)))
void rnn_fused(const float* __restrict__ x,     // [T,B,2]
               const float* __restrict__ W_ih,  // [H,2]
               const float* __restrict__ W_hh,  // [H,H]
               const float* __restrict__ b_ih,  // [H]
               const float* __restrict__ b_hh,  // [H]
               const float* __restrict__ W_out, // [1,H]
               const float* __restrict__ b_out, // [1]
               float* __restrict__ out)         // [T,B]
{
    const int b    = blockIdx.x;
    const int tid  = threadIdx.x;
    const int w    = tid >> 6;       // wave id 0..15
    const int lane = tid & 63;
    const int m    = lane & 15;      // A-row sel / B-col / D-col
    const int q    = lane >> 4;      // k-quad

    const bool hasT = (w < NT);
    const int  nA   = 16 * w + m;
    const bool colv = hasT && (nA < H);
    const bool epi  = colv && (q == 0);

    // ring[slot][hi=0/lo=1][col]; lo offset 448 B = 64 mod 128 -> the wave's
    // 8 distinct 16B A-chunks cover 32 banks: conflict-free (R11-R13: 0).
    __shared__ __align__(16) unsigned short ring[RS][2][HP];
    __shared__ float xs[2 * T];      // x column (16 KB)

    for (int i = tid; i < RS * 2 * HP; i += NTHR) (&ring[0][0][0])[i] = 0;
    for (int idx = tid; idx < T; idx += NTHR) {
        const float2 v = *(const float2*)(x + (size_t)idx * (B * 2) + 2 * b);
        xs[2 * idx] = v.x; xs[2 * idx + 1] = v.y;
    }
    __syncthreads();
    // constants in the dead k-space: cols 202/203 = 1.0 (hi buf), all slots;
    // x_0 into slot 8 (sr of step 0), cols 200/201 (hi/lo) + 204/205 mirror.
    if (tid < RS) {
        ring[tid][0][202] = 0x3C00; ring[tid][0][203] = 0x3C00;
    }
    if (tid < 2) {
        const float xv = xs[tid];
        const unsigned short xh = f2h(xv);
        const unsigned short xl = f2h(xv - h2f(xh));
        ring[8][0][200 + tid] = xh; ring[8][1][200 + tid] = xl;
        ring[8][0][204 + tid] = xh; ring[8][1][204 + tid] = xl;
    }

    // --- loop-invariant B-fragment: B[k][n] = W_hh[n][k] for k<200;
    //     k=200/201: W_ih hi; 204/205: W_ih lo; 202/203: bias hi/lo. ---
    s8v BA[KT];
    {
        float wi0 = 0.f, wi1 = 0.f, bs = 0.f;
        if (colv) {
            wi0 = W_ih[nA * 2]; wi1 = W_ih[nA * 2 + 1];
            bs  = b_ih[nA] + b_hh[nA];
        }
        const unsigned short wi0h = f2h(wi0), wi1h = f2h(wi1), bsh = f2h(bs);
        const unsigned short wi0l = f2h(wi0 - h2f(wi0h));
        const unsigned short wi1l = f2h(wi1 - h2f(wi1h));
        const unsigned short bsl  = f2h(bs - h2f(bsh));
#pragma unroll
        for (int kt = 0; kt < KT; ++kt) {
            s8v ba{};
            if (colv) {
#pragma unroll
                for (int j = 0; j < 8; ++j) {
                    const int ks = 32 * kt + 8 * q + j;
                    unsigned short v = 0;
                    if      (ks < H)    v = f2h(W_hh[nA * H + ks]);
                    else if (ks == 200) v = wi0h;
                    else if (ks == 201) v = wi1h;
                    else if (ks == 202) v = bsh;
                    else if (ks == 203) v = bsl;
                    else if (ks == 204) v = wi0l;
                    else if (ks == 205) v = wi1l;
                    ba[j] = (short)v;
                }
            }
            BA[kt] = ba;
        }
    }

    // --- head constants ---
    const float wo0 = W_out[lane];
    const float wo1 = W_out[64 + lane];
    const float wo2 = W_out[128 + lane];
    const float wo3 = (192 + lane < H) ? W_out[192 + lane] : 0.f;
    const float bo  = b_out[0];

    __syncthreads();

    float* op = out + b;

    auto drain = [&](int slot, int tout) {
        float v = (h2f(ring[slot][0][lane])     + h2f(ring[slot][1][lane]))     * wo0
                + (h2f(ring[slot][0][64+lane])  + h2f(ring[slot][1][64+lane]))  * wo1
                + (h2f(ring[slot][0][128+lane]) + h2f(ring[slot][1][128+lane])) * wo2;
        if (lane < 32)   // cols 192..223: x/1.0 junk is finite, wo3=0 there
            v += (h2f(ring[slot][0][192+lane]) + h2f(ring[slot][1][192+lane])) * wo3;
#pragma unroll
        for (int off = 32; off > 0; off >>= 1)
            v += __shfl_down(v, off, 64);
        if (lane == 0) op[(size_t)tout * B] = v + bo;
    };

    const unsigned short* ringu = &ring[0][0][0];
    const int laneoff = ((m == 1) ? HP : 0) + 8 * q;   // ushort units

    int rp = 0;                          // t % 9
    for (int t = 0; t < T; ++t) {
        // drain every 9 steps on idle waves 13..15 (slot s = h_{t-9+s});
        // extra barrier orders the subsequent rewrite of slot 0.
        if (rp == 0 && t) {
            if (w >= NT) {
                const int base = (w - NT) * 3;
                drain(base + 0, t - RS + base + 0);
                drain(base + 1, t - RS + base + 1);
                drain(base + 2, t - RS + base + 2);
            }
            __syncthreads();
        }
        const int sr = rp ? rp - 1 : RS - 1;
        const int sw = rp;

        if (hasT) {
            const unsigned short* lp = ringu + sr * (2 * HP) + laneoff;
            s8v A[KT];
#pragma unroll
            for (int kt = 0; kt < KT; ++kt) A[kt] = *(const s8v*)(lp + 32 * kt);

            f4v u = {0.f, 0.f, 0.f, 0.f};
            f4v v = {0.f, 0.f, 0.f, 0.f};
            u = __builtin_amdgcn_mfma_f32_16x16x32_f16(A[0], BA[0], u, 0, 0, 0);
            v = __builtin_amdgcn_mfma_f32_16x16x32_f16(A[4], BA[4], v, 0, 0, 0);
            u = __builtin_amdgcn_mfma_f32_16x16x32_f16(A[1], BA[1], u, 0, 0, 0);
            v = __builtin_amdgcn_mfma_f32_16x16x32_f16(A[5], BA[5], v, 0, 0, 0);
            u = __builtin_amdgcn_mfma_f32_16x16x32_f16(A[2], BA[2], u, 0, 0, 0);
            v = __builtin_amdgcn_mfma_f32_16x16x32_f16(A[6], BA[6], v, 0, 0, 0);
            u = __builtin_amdgcn_mfma_f32_16x16x32_f16(A[3], BA[3], u, 0, 0, 0);

            // epilogue: D rows 0,1 (q==0 lanes) already include x-proj+bias
            if (epi) {
                const float pre = (u[0] + u[1]) + (v[0] + v[1]);
                const float e   = __expf(2.f * pre);      // tanh, saturating
                const float th  = 1.f - 2.f / (e + 1.f);
                const unsigned short hi = f2h(th);
                ring[sw][0][nA] = hi;
                ring[sw][1][nA] = f2h(th - h2f(hi));
            }
        } else if (w == NT && lane < 2 && t + 1 < T) {
            // wave 13: stage x_{t+1} into slot sw (read next step as sr)
            const float xv = xs[2 * (t + 1) + lane];
            const unsigned short xh = f2h(xv);
            const unsigned short xl = f2h(xv - h2f(xh));
            ring[sw][0][200 + lane] = xh; ring[sw][1][200 + lane] = xl;
            ring[sw][0][204 + lane] = xh; ring[sw][1][204 + lane] = xl;
        }
        __syncthreads();
        if (++rp == RS) rp = 0;
    }

    // tail: T mod 9 = 5 steps (2043..2047) sit in slots 0..4
    const int rem = T % RS;
    if (w < rem) drain(w, T - rem + w);
}

extern "C" void kernel_launch(void* const* d_in, const int* in_sizes, int n_in,
                              void* d_out, int out_size, void* d_ws, size_t ws_size,
                              hipStream_t stream) {
    const float* x     = (const float*)d_in[0];
    const float* W_ih  = (const float*)d_in[1];
    const float* W_hh  = (const float*)d_in[2];
    const float* b_ih  = (const float*)d_in[3];
    const float* b_hh  = (const float*)d_in[4];
    const float* W_out = (const float*)d_in[5];
    const float* b_out = (const float*)d_in[6];
    float* out = (float*)d_out;

    rnn_fused<<<B, NTHR, 0, stream>>>(x, W_ih, W_hh, b_ih, b_hh, W_out, b_out, out);
}

// Round 15
// 1155.920 us; speedup vs baseline: 1.0700x; 1.0700x over previous
//
#include <hip/hip_runtime.h>
#include <hip/hip_fp16.h>

// RNN_16492674416646: h_t = tanh(x_t W_ih^T + b_ih + b_hh + h_{t-1} W_hh^T),
// out_t = h_t W_out^T + b_out. T=2048, B=128, IN=2, H=200, OUT=1, fp32.
//
// R15 = R13/R14 hybrid + zero-cost drain:
//  - 16 waves (1024 thr, 4/SIMD). Waves 0..12: one 16-col n-tile each,
//    fp16-W MFMA (7x 16x16x32), h split fp16 hi+lo on A rows 0/1.
//  - x-proj + bias live in the MFMA's dead k-space (R14, absmax-verified):
//    B[k=200/201]=W_ih hi, B[204/205]=W_ih lo, B[202/203]=bias hi/lo;
//    ring cols 200/201/204/205 carry x_t hi/lo (staged by wave 13), cols
//    202/203 hold 1.0.
//  - RING=10 slots, DRAIN PERIOD=9: drained slots (t-9..t-1)%10 NEVER
//    include the write slot t%10 -> no extra barrier; drains run on idle
//    waves 13..15 CONCURRENTLY with the MFMA step (R14's serialized
//    drain sat exposed between two barriers = the +123us regression).
//  - ONE barrier per step; tile waves run a branch-free uniform stream.
// Bank layout (R11-verified, 0 conflicts): lo offset within slot = 448 B
// = 64 mod 128 -> hi chunks banks 0-15, lo chunks 16-31 per kt.

typedef short s8v __attribute__((ext_vector_type(8)));   // 8 x fp16 bits
typedef float f4v __attribute__((ext_vector_type(4)));

static constexpr int T = 2048;
static constexpr int B = 128;
static constexpr int H = 200;
static constexpr int NTHR = 1024;  // 16 waves
static constexpr int NT  = 13;     // n-tiles of 16 (208 >= 200)
static constexpr int KT  = 7;      // k-tiles of 32 (224)
static constexpr int HP  = 224;    // padded H (k-space)
static constexpr int RS  = 10;     // ring slots
static constexpr int DP  = 9;      // drain period (RS-1: no slot collision)

__device__ __forceinline__ unsigned short f2h(float f) {
    const __half h = __float2half_rn(f);
    return *(const unsigned short*)&h;
}
__device__ __forceinline__ float h2f(unsigned short u) {
    const __half h = *(const __half*)&u;
    return __half2float(h);
}

__global__ __attribute__((amdgpu_flat_work_group_size(NTHR, NTHR),
                          amdgpu_waves_per_eu(4, 4)))
void rnn_fused(const float* __restrict__ x,     // [T,B,2]
               const float* __restrict__ W_ih,  // [H,2]
               const float* __restrict__ W_hh,  // [H,H]
               const float* __restrict__ b_ih,  // [H]
               const float* __restrict__ b_hh,  // [H]
               const float* __restrict__ W_out, // [1,H]
               const float* __restrict__ b_out, // [1]
               float* __restrict__ out)         // [T,B]
{
    const int b    = blockIdx.x;
    const int tid  = threadIdx.x;
    const int w    = tid >> 6;       // wave id 0..15
    const int lane = tid & 63;
    const int m    = lane & 15;      // A-row sel / B-col / D-col
    const int q    = lane >> 4;      // k-quad

    const bool hasT = (w < NT);
    const int  nA   = 16 * w + m;
    const bool colv = hasT && (nA < H);
    const bool epi  = colv && (q == 0);

    __shared__ __align__(16) unsigned short ring[RS][2][HP];
    __shared__ float xs[2 * T];      // x column (16 KB)

    for (int i = tid; i < RS * 2 * HP; i += NTHR) (&ring[0][0][0])[i] = 0;
    for (int idx = tid; idx < T; idx += NTHR) {
        const float2 v = *(const float2*)(x + (size_t)idx * (B * 2) + 2 * b);
        xs[2 * idx] = v.x; xs[2 * idx + 1] = v.y;
    }
    __syncthreads();
    // dead-k constants: cols 202/203 = 1.0 (hi buf) in every slot;
    // x_0 into slot RS-1 (sr of step 0), cols 200/201 + 204/205 hi/lo.
    if (tid < RS) {
        ring[tid][0][202] = 0x3C00; ring[tid][0][203] = 0x3C00;
    }
    if (tid < 2) {
        const float xv = xs[tid];
        const unsigned short xh = f2h(xv);
        const unsigned short xl = f2h(xv - h2f(xh));
        ring[RS - 1][0][200 + tid] = xh; ring[RS - 1][1][200 + tid] = xl;
        ring[RS - 1][0][204 + tid] = xh; ring[RS - 1][1][204 + tid] = xl;
    }

    // --- loop-invariant B-fragment: W_hh for k<200, W_ih/bias in dead k ---
    s8v BA[KT];
    {
        float wi0 = 0.f, wi1 = 0.f, bs = 0.f;
        if (colv) {
            wi0 = W_ih[nA * 2]; wi1 = W_ih[nA * 2 + 1];
            bs  = b_ih[nA] + b_hh[nA];
        }
        const unsigned short wi0h = f2h(wi0), wi1h = f2h(wi1), bsh = f2h(bs);
        const unsigned short wi0l = f2h(wi0 - h2f(wi0h));
        const unsigned short wi1l = f2h(wi1 - h2f(wi1h));
        const unsigned short bsl  = f2h(bs - h2f(bsh));
#pragma unroll
        for (int kt = 0; kt < KT; ++kt) {
            s8v ba{};
            if (colv) {
#pragma unroll
                for (int j = 0; j < 8; ++j) {
                    const int ks = 32 * kt + 8 * q + j;
                    unsigned short v = 0;
                    if      (ks < H)    v = f2h(W_hh[nA * H + ks]);
                    else if (ks == 200) v = wi0h;
                    else if (ks == 201) v = wi1h;
                    else if (ks == 202) v = bsh;
                    else if (ks == 203) v = bsl;
                    else if (ks == 204) v = wi0l;
                    else if (ks == 205) v = wi1l;
                    ba[j] = (short)v;
                }
            }
            BA[kt] = ba;
        }
    }

    // --- head constants ---
    const float wo0 = W_out[lane];
    const float wo1 = W_out[64 + lane];
    const float wo2 = W_out[128 + lane];
    const float wo3 = (192 + lane < H) ? W_out[192 + lane] : 0.f;
    const float bo  = b_out[0];

    __syncthreads();

    float* op = out + b;

    auto drain = [&](int slot, int tout) {
        float v = (h2f(ring[slot][0][lane])     + h2f(ring[slot][1][lane]))     * wo0
                + (h2f(ring[slot][0][64+lane])  + h2f(ring[slot][1][64+lane]))  * wo1
                + (h2f(ring[slot][0][128+lane]) + h2f(ring[slot][1][128+lane])) * wo2;
        if (lane < 32)   // cols 192..223: x/1.0 staging is finite, wo3=0 there
            v += (h2f(ring[slot][0][192+lane]) + h2f(ring[slot][1][192+lane])) * wo3;
#pragma unroll
        for (int off = 32; off > 0; off >>= 1)
            v += __shfl_down(v, off, 64);
        if (lane == 0) op[(size_t)tout * B] = v + bo;
    };

    const unsigned short* ringu = &ring[0][0][0];
    const int laneoff = ((m == 1) ? HP : 0) + 8 * q;   // ushort units
    const f4v z4 = {0.f, 0.f, 0.f, 0.f};

    int rp  = 0;                     // t % 10 (write slot)
    int rp9 = 0;                     // t % 9  (drain phase)
    for (int t = 0; t < T; ++t) {
        const int sr = rp ? rp - 1 : RS - 1;
        const int sw = rp;

        if (hasT) {
            const unsigned short* lp = ringu + sr * (2 * HP) + laneoff;
            s8v A[KT];
#pragma unroll
            for (int kt = 0; kt < KT; ++kt) A[kt] = *(const s8v*)(lp + 32 * kt);

            f4v u = __builtin_amdgcn_mfma_f32_16x16x32_f16(A[0], BA[0], z4, 0, 0, 0);
            f4v v = __builtin_amdgcn_mfma_f32_16x16x32_f16(A[4], BA[4], z4, 0, 0, 0);
            u = __builtin_amdgcn_mfma_f32_16x16x32_f16(A[1], BA[1], u, 0, 0, 0);
            v = __builtin_amdgcn_mfma_f32_16x16x32_f16(A[5], BA[5], v, 0, 0, 0);
            u = __builtin_amdgcn_mfma_f32_16x16x32_f16(A[2], BA[2], u, 0, 0, 0);
            v = __builtin_amdgcn_mfma_f32_16x16x32_f16(A[6], BA[6], v, 0, 0, 0);
            u = __builtin_amdgcn_mfma_f32_16x16x32_f16(A[3], BA[3], u, 0, 0, 0);

            if (epi) {   // D rows 0,1 already include x-proj + bias
                const float pre = (u[0] + u[1]) + (v[0] + v[1]);
                const float e   = __expf(2.f * pre);      // tanh, saturating
                const float th  = 1.f - 2.f / (e + 1.f);
                const unsigned short hi = f2h(th);
                ring[sw][0][nA] = hi;
                ring[sw][1][nA] = f2h(th - h2f(hi));
            }
        } else {
            if (w == NT && lane < 2 && t + 1 < T) {
                // stage x_{t+1} into slot sw (becomes sr next step)
                const float xv = xs[2 * (t + 1) + lane];
                const unsigned short xh = f2h(xv);
                const unsigned short xl = f2h(xv - h2f(xh));
                ring[sw][0][200 + lane] = xh; ring[sw][1][200 + lane] = xl;
                ring[sw][0][204 + lane] = xh; ring[sw][1][204 + lane] = xl;
            }
            // drains: outputs t-9..t-1 live in slots (rp+1+i)%10, i=0..8 --
            // never slot sw, never touched by this step's writers ->
            // concurrent with compute, no extra barrier.
            if (rp9 == 0 && t) {
                const int base = (w - NT) * 3;             // 0 / 3 / 6
#pragma unroll
                for (int i = 0; i < 3; ++i) {
                    const int idx = base + i;
                    int slot = rp + 1 + idx;
                    if (slot >= RS) slot -= RS;
                    drain(slot, t - DP + idx);
                }
            }
        }
        __syncthreads();
        rp  = (rp  + 1 == RS) ? 0 : rp  + 1;
        rp9 = (rp9 + 1 == DP) ? 0 : rp9 + 1;
    }

    // tail: outputs T-rem..T-1 (rem = ((T-1) mod 9)+1 = 5) in slots t%10
    const int rem = ((T - 1) % DP) + 1;
    if (w < rem) {
        const int tout = T - rem + w;
        drain(tout % RS, tout);
    }
}

extern "C" void kernel_launch(void* const* d_in, const int* in_sizes, int n_in,
                              void* d_out, int out_size, void* d_ws, size_t ws_size,
                              hipStream_t stream) {
    const float* x     = (const float*)d_in[0];
    const float* W_ih  = (const float*)d_in[1];
    const float* W_hh  = (const float*)d_in[2];
    const float* b_ih  = (const float*)d_in[3];
    const float* b_hh  = (const float*)d_in[4];
    const float* W_out = (const float*)d_in[5];
    const float* b_out = (const float*)d_in[6];
    float* out = (float*)d_out;

    rnn_fused<<<B, NTHR, 0, stream>>>(x, W_ih, W_hh, b_ih, b_hh, W_out, b_out, out);
}